// Round 3
// baseline (2478.801 us; speedup 1.0000x reference)
//
#include <hip/hip_runtime.h>

// Problem constants (fixed by the reference)
#define ASPECTS 16
#define ADIM    128
#define KDIM    128
#define HIDDEN  2048   // ASPECTS*ADIM
#define GRID    4096   // persistent blocks; each handles n/GRID nodes
#define SLOTS   64     // attsum partial-sum slots (1 atomic per thread per block total)

using f32x4  = __attribute__((ext_vector_type(4))) float;
using bf16x8 = __attribute__((ext_vector_type(8))) short;

union BF8U { int i[4]; bf16x8 v; };

// Split 8 fp32 into truncated-bf16 hi + bf16(lo) residual fragments.
// x = hi + lo + O(2^-16 |x|)  -> 3-term MFMA gives fp32-equivalent products.
__device__ __forceinline__ void split8(float4 q0, float4 q1, bf16x8& hi, bf16x8& lo) {
    float xs[8] = {q0.x, q0.y, q0.z, q0.w, q1.x, q1.y, q1.z, q1.w};
    BF8U H, L;
#pragma unroll
    for (int p = 0; p < 4; ++p) {
        union { float f; unsigned u; } a0, a1, h0, h1, r0, r1;
        a0.f = xs[2 * p]; a1.f = xs[2 * p + 1];
        h0.u = a0.u & 0xffff0000u;
        h1.u = a1.u & 0xffff0000u;
        r0.f = a0.f - h0.f;           // exact (same exponent, |r| < 2^-8 |x|)
        r1.f = a1.f - h1.f;
        H.i[p] = (int)((h0.u >> 16) | h1.u);
        L.i[p] = (int)((r0.u >> 16) | (r1.u & 0xffff0000u));
    }
    hi = H.v; lo = L.v;
}

__device__ __forceinline__ float fast_tanh(float x) {
    // tanh(x) = 1 - 2/(e^{2x}+1); exact at +-inf, ~1e-7 error elsewhere
    return 1.0f - __fdividef(2.0f, __expf(2.0f * x) + 1.0f);
}

// ---------------------------------------------------------------------------
// prep: wbt[d][a] = sum_j w_b[d][j] * team[a*128+j]
//       wtt[k][a] = sum_j w_t[k][j] * team[a*128+j]
// grid 16 (a), block 128 (row index)
// ---------------------------------------------------------------------------
__global__ void prep_kernel(const float* __restrict__ team,
                            const float* __restrict__ w_b,
                            const float* __restrict__ w_t,
                            float* __restrict__ wbt,   // [128][16]
                            float* __restrict__ wtt) { // [128][16]
    int a = blockIdx.x;
    int i = threadIdx.x;
    __shared__ float ta[ADIM];
    ta[i] = team[a * ADIM + i];
    __syncthreads();
    const float* wbr = w_b + i * ADIM;
    const float* wtr = w_t + i * ADIM;
    float s1 = 0.f, s2 = 0.f;
#pragma unroll 4
    for (int j = 0; j < ADIM; ++j) {
        s1 += wbr[j] * ta[j];
        s2 += wtr[j] * ta[j];
    }
    wbt[i * ASPECTS + a] = s1;
    wtt[i * ASPECTS + a] = s2;
}

// ---------------------------------------------------------------------------
// prep2: pack wbt into MFMA B-fragments (hi/lo bf16) and transpose w_ht/w_hp.
// B-frag for mfma_f32_16x16x32_bf16: lane l -> col=l&15, k = (l>>4)*8 + j
// grid 1, block 256
// ---------------------------------------------------------------------------
__global__ void prep2_kernel(const float* __restrict__ wbt,   // [128][16]
                             const float* __restrict__ w_ht,  // [128][16]
                             const float* __restrict__ w_hp,  // [128][16]
                             unsigned short* __restrict__ wf_hi,  // [4][64][8]
                             unsigned short* __restrict__ wf_lo,
                             float* __restrict__ whtT,   // [16][128]
                             float* __restrict__ whpT) { // [16][128]
    int t = threadIdx.x;
    int s = t >> 6, l = t & 63;
    int b = l & 15, g = l >> 4;
#pragma unroll
    for (int j = 0; j < 8; ++j) {
        int d = s * 32 + g * 8 + j;
        union { float f; unsigned u; } x, h, r;
        x.f = wbt[d * ASPECTS + b];
        h.u = x.u & 0xffff0000u;
        r.f = x.f - h.f;
        wf_hi[(s * 64 + l) * 8 + j] = (unsigned short)(x.u >> 16);
        wf_lo[(s * 64 + l) * 8 + j] = (unsigned short)(r.u >> 16);
    }
#pragma unroll
    for (int j = 0; j < 8; ++j) {
        int flat = t * 8 + j;           // 0..2047 = a*128 + kk
        int a = flat >> 7, kk = flat & 127;
        whtT[flat] = w_ht[kk * ASPECTS + a];
        whpT[flat] = w_hp[kk * ASPECTS + a];
    }
}

// ---------------------------------------------------------------------------
// main: persistent blocks, 256 threads (4 waves), grid-stride over nodes.
// Steps 1+2 on MFMA (split-bf16, fp32-accurate); steps 3-5 on VALU.
// ---------------------------------------------------------------------------
__global__ __launch_bounds__(256, 3)
void coattn_main(const float* __restrict__ player,  // [N][2048]
                 const float* __restrict__ w_p,     // [128][128]
                 const float* __restrict__ wtt,     // [128][16]
                 const float* __restrict__ whtT,    // [16][128]
                 const float* __restrict__ whpT,    // [16][128]
                 const unsigned short* __restrict__ wbtf_hi,
                 const unsigned short* __restrict__ wbtf_lo,
                 float* __restrict__ pout,          // [N][2048]
                 float* __restrict__ attsum,        // [SLOTS][256]
                 int total) {
    const int tid = threadIdx.x;
    const int l   = tid & 63;       // lane in wave
    const int wv  = tid >> 6;       // wave 0..3

    __shared__ __align__(16) float sp[ASPECTS][132];     // player aspects (fp32)
    __shared__ __align__(16) float C_lds[ASPECTS][20];   // tanh(p . wbt)
    __shared__ __align__(16) float wpp[KDIM][20];        // wp_p[k][a]
    __shared__ __align__(16) float tcoT[ASPECTS][132];   // team_co transposed [b][k]
    __shared__ __align__(16) float pcoT[ASPECTS][132];   // player_co transposed
    __shared__ float attp[ASPECTS][17];

    // ---- persistent A-fragments of w_p: wave wv owns k-rows [wv*32, wv*32+32) ----
    // A-frag: lane l -> row = tile*16 + (l&15), k = s*32 + (l>>4)*8 + j
    bf16x8 ahi0[4], alo0[4], ahi1[4], alo1[4];
    {
        int ar = l & 15, ag = l >> 4;
        const float* w0 = w_p + ((wv * 2 + 0) * 16 + ar) * ADIM + ag * 8;
        const float* w1 = w_p + ((wv * 2 + 1) * 16 + ar) * ADIM + ag * 8;
#pragma unroll
        for (int s = 0; s < 4; ++s) {
            float4 q0 = *(const float4*)(w0 + s * 32);
            float4 q1 = *(const float4*)(w0 + s * 32 + 4);
            split8(q0, q1, ahi0[s], alo0[s]);
            float4 r0 = *(const float4*)(w1 + s * 32);
            float4 r1 = *(const float4*)(w1 + s * 32 + 4);
            split8(r0, r1, ahi1[s], alo1[s]);
        }
    }

    float att_acc = 0.0f;

    int node = blockIdx.x;
    float4 pf0, pf1;
    if (node < total) {
        const float4* pr = (const float4*)(player + (size_t)node * HIDDEN);
        pf0 = pr[tid];
        pf1 = pr[tid + 256];
    }

    for (; node < total; node += GRID) {
        __syncthreads();   // previous iteration's sp/attp readers done
        {
            int i0 = tid, i1 = tid + 256;
            *(float4*)&sp[i0 >> 5][(i0 & 31) * 4] = pf0;
            *(float4*)&sp[i1 >> 5][(i1 & 31) * 4] = pf1;
        }
        int nxt = node + GRID;
        if (nxt < total) {   // prefetch next node during compute
            const float4* pr = (const float4*)(player + (size_t)nxt * HIDDEN);
            pf0 = pr[tid];
            pf1 = pr[tid + 256];
        }
        __syncthreads();   // sp ready

        // ---- MFMA: wpp = w_p @ P^T (all waves), C = tanh(P @ wbt) (wave 0) ----
        f32x4 accW0 = {0.f, 0.f, 0.f, 0.f};
        f32x4 accW1 = {0.f, 0.f, 0.f, 0.f};
        f32x4 accC  = {0.f, 0.f, 0.f, 0.f};
        {
            int br = l & 15, bg = l >> 4;
#pragma unroll
            for (int s = 0; s < 4; ++s) {
                const float* src = &sp[br][s * 32 + bg * 8];
                float4 q0 = *(const float4*)(src);
                float4 q1 = *(const float4*)(src + 4);
                bf16x8 bhi, blo;
                split8(q0, q1, bhi, blo);
                accW0 = __builtin_amdgcn_mfma_f32_16x16x32_bf16(ahi0[s], bhi, accW0, 0, 0, 0);
                accW1 = __builtin_amdgcn_mfma_f32_16x16x32_bf16(ahi1[s], bhi, accW1, 0, 0, 0);
                if (wv == 0) {
                    bf16x8 wh = *(const bf16x8*)&wbtf_hi[(s * 64 + l) * 8];
                    bf16x8 wl = *(const bf16x8*)&wbtf_lo[(s * 64 + l) * 8];
                    accC = __builtin_amdgcn_mfma_f32_16x16x32_bf16(bhi, wh, accC, 0, 0, 0);
                    accC = __builtin_amdgcn_mfma_f32_16x16x32_bf16(bhi, wl, accC, 0, 0, 0);
                    accC = __builtin_amdgcn_mfma_f32_16x16x32_bf16(blo, wh, accC, 0, 0, 0);
                }
                accW0 = __builtin_amdgcn_mfma_f32_16x16x32_bf16(ahi0[s], blo, accW0, 0, 0, 0);
                accW1 = __builtin_amdgcn_mfma_f32_16x16x32_bf16(ahi1[s], blo, accW1, 0, 0, 0);
                accW0 = __builtin_amdgcn_mfma_f32_16x16x32_bf16(alo0[s], bhi, accW0, 0, 0, 0);
                accW1 = __builtin_amdgcn_mfma_f32_16x16x32_bf16(alo1[s], bhi, accW1, 0, 0, 0);
            }
            // C/D layout (HW-verified): col = lane&15, row = (lane>>4)*4 + reg
            int g = l >> 4, col = l & 15;
            if (wv == 0) {
#pragma unroll
                for (int r = 0; r < 4; ++r)
                    C_lds[g * 4 + r][col] = fast_tanh(accC[r]);
            }
            int row0 = (wv * 2 + 0) * 16 + g * 4;
            int row1 = (wv * 2 + 1) * 16 + g * 4;
#pragma unroll
            for (int r = 0; r < 4; ++r) wpp[row0 + r][col] = accW0[r];
#pragma unroll
            for (int r = 0; r < 4; ++r) wpp[row1 + r][col] = accW1[r];
        }
        __syncthreads();

        // ---- step 3: tco/pco; thread owns (k, half-of-b) ----
        {
            int k = tid & 127, h = tid >> 7;   // h wave-uniform
            float wr[16];
#pragma unroll
            for (int q = 0; q < 4; ++q)
                *(float4*)&wr[q * 4] = *(const float4*)&wpp[k][q * 4];
            float4 t0 = *(const float4*)&wtt[k * ASPECTS];
            float4 t1 = *(const float4*)&wtt[k * ASPECTS + 4];
            float4 t2 = *(const float4*)&wtt[k * ASPECTS + 8];
            float4 t3 = *(const float4*)&wtt[k * ASPECTS + 12];
            float st[8], sv[8];
            if (h == 0) {
                st[0]=t0.x; st[1]=t0.y; st[2]=t0.z; st[3]=t0.w;
                st[4]=t1.x; st[5]=t1.y; st[6]=t1.z; st[7]=t1.w;
                sv[0]=wr[0]; sv[1]=wr[1]; sv[2]=wr[2]; sv[3]=wr[3];
                sv[4]=wr[4]; sv[5]=wr[5]; sv[6]=wr[6]; sv[7]=wr[7];
            } else {
                st[0]=t2.x; st[1]=t2.y; st[2]=t2.z; st[3]=t2.w;
                st[4]=t3.x; st[5]=t3.y; st[6]=t3.z; st[7]=t3.w;
                sv[0]=wr[8];  sv[1]=wr[9];  sv[2]=wr[10]; sv[3]=wr[11];
                sv[4]=wr[12]; sv[5]=wr[13]; sv[6]=wr[14]; sv[7]=wr[15];
            }
#pragma unroll
            for (int R = 0; R < 16; ++R) {
                float4 cO0 = *(const float4*)&C_lds[R][h * 8];
                float4 cO1 = *(const float4*)&C_lds[R][h * 8 + 4];
                float wR = wr[R];
                st[0] += wR * cO0.x; st[1] += wR * cO0.y;
                st[2] += wR * cO0.z; st[3] += wR * cO0.w;
                st[4] += wR * cO1.x; st[5] += wR * cO1.y;
                st[6] += wR * cO1.z; st[7] += wR * cO1.w;
                if ((R >> 3) == h) {   // wave-uniform branch
                    float4 c0 = *(const float4*)&C_lds[R][0];
                    float4 c1 = *(const float4*)&C_lds[R][4];
                    float4 c2 = *(const float4*)&C_lds[R][8];
                    float4 c3 = *(const float4*)&C_lds[R][12];
                    float d = c0.x*t0.x + c0.y*t0.y + c0.z*t0.z + c0.w*t0.w
                            + c1.x*t1.x + c1.y*t1.y + c1.z*t1.z + c1.w*t1.w
                            + c2.x*t2.x + c2.y*t2.y + c2.z*t2.z + c2.w*t2.w
                            + c3.x*t3.x + c3.y*t3.y + c3.z*t3.z + c3.w*t3.w;
                    sv[R & 7] += d;
                }
            }
#pragma unroll
            for (int b = 0; b < 8; ++b) {
                tcoT[h * 8 + b][k] = fast_tanh(st[b]);
                pcoT[h * 8 + b][k] = fast_tanh(sv[b]);
            }
        }
        __syncthreads();

        // ---- step 4: scores + shuffle-softmax over b (no barriers) ----
        {
            int a = tid >> 4, b = tid & 15;
            const float* hT = whtT + a * KDIM;
            const float* pT = whpT + a * KDIM;
            float s_t = 0.f, s_v = 0.f;
#pragma unroll 8
            for (int kk = 0; kk < KDIM; kk += 4) {
                float4 ht = *(const float4*)(hT + kk);
                float4 hp = *(const float4*)(pT + kk);
                float4 tc = *(const float4*)&tcoT[b][kk];
                float4 pc = *(const float4*)&pcoT[b][kk];
                s_t += ht.x*tc.x + ht.y*tc.y + ht.z*tc.z + ht.w*tc.w;
                s_v += hp.x*pc.x + hp.y*pc.y + hp.z*pc.z + hp.w*pc.w;
            }
            float mt = s_t, mv = s_v;
#pragma unroll
            for (int o = 8; o; o >>= 1) {
                mt = fmaxf(mt, __shfl_xor(mt, o));
                mv = fmaxf(mv, __shfl_xor(mv, o));
            }
            float et = __expf(s_t - mt), ev = __expf(s_v - mv);
            float dt = et, dv = ev;
#pragma unroll
            for (int o = 8; o; o >>= 1) {
                dt += __shfl_xor(dt, o);
                dv += __shfl_xor(dv, o);
            }
            et = __fdividef(et, dt);
            ev = __fdividef(ev, dv);
            att_acc += et;          // team attention only needs the sum over n
            attp[a][b] = ev;
        }
        __syncthreads();

        // ---- step 5: player_out[a][d] = sum_b attp[a][b] * sp[b][d] ----
        {
            int a = tid >> 4, c = tid & 15;
            float4 o0 = {0.f, 0.f, 0.f, 0.f}, o1 = {0.f, 0.f, 0.f, 0.f};
#pragma unroll
            for (int b = 0; b < ASPECTS; ++b) {
                float w = attp[a][b];
                float4 s0 = *(const float4*)&sp[b][c * 4];
                float4 s1 = *(const float4*)&sp[b][c * 4 + 64];
                o0.x += w * s0.x; o0.y += w * s0.y; o0.z += w * s0.z; o0.w += w * s0.w;
                o1.x += w * s1.x; o1.y += w * s1.y; o1.z += w * s1.z; o1.w += w * s1.w;
            }
            float* orow = pout + (size_t)node * HIDDEN + a * ADIM;
            *(float4*)&orow[c * 4]      = o0;
            *(float4*)&orow[c * 4 + 64] = o1;
        }
    }

    atomicAdd(&attsum[(blockIdx.x & (SLOTS - 1)) * 256 + tid], att_acc);
}

// ---------------------------------------------------------------------------
// epilogue: out0[a][d] = (1/N) * sum_b (sum_n att_t[n][a][b]) * team[b*128+d]
// ---------------------------------------------------------------------------
__global__ void epi_kernel(const float* __restrict__ team,
                           const float* __restrict__ attsum,
                           float* __restrict__ out0, float inv_n) {
    int a = blockIdx.x;
    int tid = threadIdx.x;
    __shared__ float ab[ASPECTS];
    if (tid < ASPECTS) {
        float s = 0.f;
        for (int slot = 0; slot < SLOTS; ++slot)
            s += attsum[slot * 256 + a * ASPECTS + tid];
        ab[tid] = s * inv_n;
    }
    __syncthreads();
    float o = 0.f;
#pragma unroll
    for (int b = 0; b < ASPECTS; ++b)
        o += ab[b] * team[b * ADIM + tid];
    out0[a * ADIM + tid] = o;
}

extern "C" void kernel_launch(void* const* d_in, const int* in_sizes, int n_in,
                              void* d_out, int out_size, void* d_ws, size_t ws_size,
                              hipStream_t stream) {
    const float* team   = (const float*)d_in[0];
    const float* player = (const float*)d_in[1];
    const float* w_b    = (const float*)d_in[2];
    const float* w_t    = (const float*)d_in[3];
    const float* w_p    = (const float*)d_in[4];
    const float* w_ht   = (const float*)d_in[5];
    const float* w_hp   = (const float*)d_in[6];
    float* out = (float*)d_out;

    int n = in_sizes[1] / HIDDEN;   // 32768

    // Workspace layout: 26624 floats total (106 KB) — well under the
    // baseline-proven 69632-float footprint, in case ws_size is tight.
    float* wbt    = (float*)d_ws;              // 2048
    float* wtt    = wbt + 2048;                // 2048
    float* attsum = wtt + 2048;                // SLOTS*256 = 16384
    float* whtT   = attsum + SLOTS * 256;      // 2048
    float* whpT   = whtT + 2048;               // 2048
    unsigned short* wbtf_hi = (unsigned short*)(whpT + 2048);  // 2048 shorts
    unsigned short* wbtf_lo = wbtf_hi + 2048;                  // 2048 shorts

    hipMemsetAsync(attsum, 0, SLOTS * 256 * sizeof(float), stream);
    prep_kernel<<<ASPECTS, ADIM, 0, stream>>>(team, w_b, w_t, wbt, wtt);
    prep2_kernel<<<1, 256, 0, stream>>>(wbt, w_ht, w_hp, wbtf_hi, wbtf_lo, whtT, whpT);
    coattn_main<<<GRID, 256, 0, stream>>>(player, w_p, wtt, whtT, whpT,
                                          wbtf_hi, wbtf_lo,
                                          out + HIDDEN, attsum, n);
    epi_kernel<<<ASPECTS, ADIM, 0, stream>>>(team, attsum, out, 1.0f / (float)n);
}

// Round 4
// 2473.720 us; speedup vs baseline: 1.0021x; 1.0021x over previous
//
#include <hip/hip_runtime.h>

// Problem constants (fixed by the reference)
#define ASPECTS 16
#define ADIM    128
#define KDIM    128
#define HIDDEN  2048   // ASPECTS*ADIM
#define GRID    4096   // persistent blocks; each handles n/GRID nodes
#define SLOTS   64     // attsum partial-sum slots (1 atomic per thread per block total)

using f32x4  = __attribute__((ext_vector_type(4))) float;
using i32x4  = __attribute__((ext_vector_type(4))) int;
using bf16x8 = __attribute__((ext_vector_type(8))) short;

// Split two fp32 into packed (bf16-hi, bf16-lo-residual) words.
// Pure scalar bit-ops -> stays in registers (no union/array allocas).
__device__ __forceinline__ void split2(float a, float b, int& hi, int& lo) {
    unsigned ua = __float_as_uint(a);
    unsigned ub = __float_as_uint(b);
    float ra = a - __uint_as_float(ua & 0xffff0000u);   // exact residual
    float rb = b - __uint_as_float(ub & 0xffff0000u);
    hi = (int)((ua >> 16) | (ub & 0xffff0000u));
    lo = (int)((__float_as_uint(ra) >> 16) | (__float_as_uint(rb) & 0xffff0000u));
}

// 8 fp32 -> hi/lo bf16x8 fragments; x = hi + lo + O(2^-16 |x|).
__device__ __forceinline__ void split8(float4 q0, float4 q1, bf16x8& hi, bf16x8& lo) {
    int h0, l0, h1, l1, h2, l2, h3, l3;
    split2(q0.x, q0.y, h0, l0);
    split2(q0.z, q0.w, h1, l1);
    split2(q1.x, q1.y, h2, l2);
    split2(q1.z, q1.w, h3, l3);
    i32x4 H = {h0, h1, h2, h3};
    i32x4 L = {l0, l1, l2, l3};
    hi = __builtin_bit_cast(bf16x8, H);
    lo = __builtin_bit_cast(bf16x8, L);
}

__device__ __forceinline__ float fast_tanh(float x) {
    // tanh(x) = 1 - 2/(e^{2x}+1); exact at +-inf, ~1e-7 error elsewhere
    return 1.0f - __fdividef(2.0f, __expf(2.0f * x) + 1.0f);
}

// ---------------------------------------------------------------------------
// prep: wbt[d][a] = sum_j w_b[d][j] * team[a*128+j]
//       wtt[k][a] = sum_j w_t[k][j] * team[a*128+j]
// grid 16 (a), block 128 (row index)
// ---------------------------------------------------------------------------
__global__ void prep_kernel(const float* __restrict__ team,
                            const float* __restrict__ w_b,
                            const float* __restrict__ w_t,
                            float* __restrict__ wbt,   // [128][16]
                            float* __restrict__ wtt) { // [128][16]
    int a = blockIdx.x;
    int i = threadIdx.x;
    __shared__ float ta[ADIM];
    ta[i] = team[a * ADIM + i];
    __syncthreads();
    const float* wbr = w_b + i * ADIM;
    const float* wtr = w_t + i * ADIM;
    float s1 = 0.f, s2 = 0.f;
#pragma unroll 4
    for (int j = 0; j < ADIM; ++j) {
        s1 += wbr[j] * ta[j];
        s2 += wtr[j] * ta[j];
    }
    wbt[i * ASPECTS + a] = s1;
    wtt[i * ASPECTS + a] = s2;
}

// ---------------------------------------------------------------------------
// prep2: pack wbt into MFMA B-fragments (hi/lo bf16) and transpose w_ht/w_hp.
// B-frag for mfma_f32_16x16x32_bf16: lane l -> col=l&15, k = (l>>4)*8 + j
// grid 1, block 256
// ---------------------------------------------------------------------------
__global__ void prep2_kernel(const float* __restrict__ wbt,   // [128][16]
                             const float* __restrict__ w_ht,  // [128][16]
                             const float* __restrict__ w_hp,  // [128][16]
                             unsigned short* __restrict__ wf_hi,  // [4][64][8]
                             unsigned short* __restrict__ wf_lo,
                             float* __restrict__ whtT,   // [16][128]
                             float* __restrict__ whpT) { // [16][128]
    int t = threadIdx.x;
    int s = t >> 6, l = t & 63;
    int b = l & 15, g = l >> 4;
#pragma unroll
    for (int j = 0; j < 8; ++j) {
        int d = s * 32 + g * 8 + j;
        float x = wbt[d * ASPECTS + b];
        unsigned u = __float_as_uint(x);
        float r = x - __uint_as_float(u & 0xffff0000u);
        wf_hi[(s * 64 + l) * 8 + j] = (unsigned short)(u >> 16);
        wf_lo[(s * 64 + l) * 8 + j] = (unsigned short)(__float_as_uint(r) >> 16);
    }
#pragma unroll
    for (int j = 0; j < 8; ++j) {
        int flat = t * 8 + j;           // 0..2047 = a*128 + kk
        int a = flat >> 7, kk = flat & 127;
        whtT[flat] = w_ht[kk * ASPECTS + a];
        whpT[flat] = w_hp[kk * ASPECTS + a];
    }
}

// ---------------------------------------------------------------------------
// main: persistent blocks, 256 threads (4 waves), grid-stride over nodes.
// Steps 1+2 on MFMA (split-bf16, fp32-accurate); steps 3-5 on VALU.
// ---------------------------------------------------------------------------
__global__ __launch_bounds__(256, 3)
void coattn_main(const float* __restrict__ player,  // [N][2048]
                 const float* __restrict__ w_p,     // [128][128]
                 const float* __restrict__ wtt,     // [128][16]
                 const float* __restrict__ whtT,    // [16][128]
                 const float* __restrict__ whpT,    // [16][128]
                 const unsigned short* __restrict__ wbtf_hi,
                 const unsigned short* __restrict__ wbtf_lo,
                 float* __restrict__ pout,          // [N][2048]
                 float* __restrict__ attsum,        // [SLOTS][256]
                 int total) {
    const int tid = threadIdx.x;
    const int l   = tid & 63;       // lane in wave
    const int wv  = tid >> 6;       // wave 0..3

    __shared__ __align__(16) float sp[ASPECTS][132];     // player aspects (fp32)
    __shared__ __align__(16) float C_lds[ASPECTS][20];   // tanh(p . wbt)
    __shared__ __align__(16) float wpp[KDIM][20];        // wp_p[k][a]
    __shared__ __align__(16) float tcoT[ASPECTS][132];   // team_co transposed [b][k]
    __shared__ __align__(16) float pcoT[ASPECTS][132];   // player_co transposed
    __shared__ float attp[ASPECTS][17];

    // ---- persistent A-fragments of w_p: wave wv owns k-rows [wv*32, wv*32+32) ----
    // A-frag: lane l -> row = tile*16 + (l&15), k = s*32 + (l>>4)*8 + j
    bf16x8 ahi0[4], alo0[4], ahi1[4], alo1[4];
    {
        int ar = l & 15, ag = l >> 4;
        const float* w0 = w_p + ((wv * 2 + 0) * 16 + ar) * ADIM + ag * 8;
        const float* w1 = w_p + ((wv * 2 + 1) * 16 + ar) * ADIM + ag * 8;
#pragma unroll
        for (int s = 0; s < 4; ++s) {
            float4 q0 = *(const float4*)(w0 + s * 32);
            float4 q1 = *(const float4*)(w0 + s * 32 + 4);
            split8(q0, q1, ahi0[s], alo0[s]);
            float4 r0 = *(const float4*)(w1 + s * 32);
            float4 r1 = *(const float4*)(w1 + s * 32 + 4);
            split8(r0, r1, ahi1[s], alo1[s]);
        }
    }

    float att_acc = 0.0f;

    int node = blockIdx.x;
    float4 pf0, pf1;
    if (node < total) {
        const float4* pr = (const float4*)(player + (size_t)node * HIDDEN);
        pf0 = pr[tid];
        pf1 = pr[tid + 256];
    }

    for (; node < total; node += GRID) {
        __syncthreads();   // previous iteration's sp/attp readers done
        {
            int i0 = tid, i1 = tid + 256;
            *(float4*)&sp[i0 >> 5][(i0 & 31) * 4] = pf0;
            *(float4*)&sp[i1 >> 5][(i1 & 31) * 4] = pf1;
        }
        int nxt = node + GRID;
        if (nxt < total) {   // prefetch next node during compute
            const float4* pr = (const float4*)(player + (size_t)nxt * HIDDEN);
            pf0 = pr[tid];
            pf1 = pr[tid + 256];
        }
        __syncthreads();   // sp ready

        // ---- MFMA: wpp = w_p @ P^T (all waves), C = tanh(P @ wbt) (wave 0) ----
        f32x4 accW0 = {0.f, 0.f, 0.f, 0.f};
        f32x4 accW1 = {0.f, 0.f, 0.f, 0.f};
        f32x4 accC  = {0.f, 0.f, 0.f, 0.f};
        {
            int br = l & 15, bg = l >> 4;
#pragma unroll
            for (int s = 0; s < 4; ++s) {
                const float* src = &sp[br][s * 32 + bg * 8];
                float4 q0 = *(const float4*)(src);
                float4 q1 = *(const float4*)(src + 4);
                bf16x8 bhi, blo;
                split8(q0, q1, bhi, blo);
                accW0 = __builtin_amdgcn_mfma_f32_16x16x32_bf16(ahi0[s], bhi, accW0, 0, 0, 0);
                accW1 = __builtin_amdgcn_mfma_f32_16x16x32_bf16(ahi1[s], bhi, accW1, 0, 0, 0);
                if (wv == 0) {
                    bf16x8 wh = *(const bf16x8*)&wbtf_hi[(s * 64 + l) * 8];
                    bf16x8 wl = *(const bf16x8*)&wbtf_lo[(s * 64 + l) * 8];
                    accC = __builtin_amdgcn_mfma_f32_16x16x32_bf16(bhi, wh, accC, 0, 0, 0);
                    accC = __builtin_amdgcn_mfma_f32_16x16x32_bf16(bhi, wl, accC, 0, 0, 0);
                    accC = __builtin_amdgcn_mfma_f32_16x16x32_bf16(blo, wh, accC, 0, 0, 0);
                }
                accW0 = __builtin_amdgcn_mfma_f32_16x16x32_bf16(ahi0[s], blo, accW0, 0, 0, 0);
                accW1 = __builtin_amdgcn_mfma_f32_16x16x32_bf16(ahi1[s], blo, accW1, 0, 0, 0);
                accW0 = __builtin_amdgcn_mfma_f32_16x16x32_bf16(alo0[s], bhi, accW0, 0, 0, 0);
                accW1 = __builtin_amdgcn_mfma_f32_16x16x32_bf16(alo1[s], bhi, accW1, 0, 0, 0);
            }
            // C/D layout (harness-validated): col = lane&15, row = (lane>>4)*4 + reg
            int g = l >> 4, col = l & 15;
            if (wv == 0) {
#pragma unroll
                for (int r = 0; r < 4; ++r)
                    C_lds[g * 4 + r][col] = fast_tanh(accC[r]);
            }
            int row0 = (wv * 2 + 0) * 16 + g * 4;
            int row1 = (wv * 2 + 1) * 16 + g * 4;
#pragma unroll
            for (int r = 0; r < 4; ++r) wpp[row0 + r][col] = accW0[r];
#pragma unroll
            for (int r = 0; r < 4; ++r) wpp[row1 + r][col] = accW1[r];
        }
        __syncthreads();

        // ---- step 3: tco/pco; thread owns (k, half-of-b) ----
        {
            int k = tid & 127, h = tid >> 7;   // h wave-uniform
            float4 w0 = *(const float4*)&wpp[k][0];
            float4 w1 = *(const float4*)&wpp[k][4];
            float4 w2 = *(const float4*)&wpp[k][8];
            float4 w3 = *(const float4*)&wpp[k][12];
            float4 t0 = *(const float4*)&wtt[k * ASPECTS];
            float4 t1 = *(const float4*)&wtt[k * ASPECTS + 4];
            float4 t2 = *(const float4*)&wtt[k * ASPECTS + 8];
            float4 t3 = *(const float4*)&wtt[k * ASPECTS + 12];
            float st[8], sv[8];
            if (h == 0) {
                st[0]=t0.x; st[1]=t0.y; st[2]=t0.z; st[3]=t0.w;
                st[4]=t1.x; st[5]=t1.y; st[6]=t1.z; st[7]=t1.w;
                sv[0]=w0.x; sv[1]=w0.y; sv[2]=w0.z; sv[3]=w0.w;
                sv[4]=w1.x; sv[5]=w1.y; sv[6]=w1.z; sv[7]=w1.w;
            } else {
                st[0]=t2.x; st[1]=t2.y; st[2]=t2.z; st[3]=t2.w;
                st[4]=t3.x; st[5]=t3.y; st[6]=t3.z; st[7]=t3.w;
                sv[0]=w2.x; sv[1]=w2.y; sv[2]=w2.z; sv[3]=w2.w;
                sv[4]=w3.x; sv[5]=w3.y; sv[6]=w3.z; sv[7]=w3.w;
            }
#pragma unroll
            for (int R = 0; R < 16; ++R) {
                float wR = (R < 4)  ? (R == 0 ? w0.x : R == 1 ? w0.y : R == 2 ? w0.z : w0.w)
                         : (R < 8)  ? (R == 4 ? w1.x : R == 5 ? w1.y : R == 6 ? w1.z : w1.w)
                         : (R < 12) ? (R == 8 ? w2.x : R == 9 ? w2.y : R == 10 ? w2.z : w2.w)
                                    : (R == 12 ? w3.x : R == 13 ? w3.y : R == 14 ? w3.z : w3.w);
                float4 cO0 = *(const float4*)&C_lds[R][h * 8];
                float4 cO1 = *(const float4*)&C_lds[R][h * 8 + 4];
                st[0] += wR * cO0.x; st[1] += wR * cO0.y;
                st[2] += wR * cO0.z; st[3] += wR * cO0.w;
                st[4] += wR * cO1.x; st[5] += wR * cO1.y;
                st[6] += wR * cO1.z; st[7] += wR * cO1.w;
                if ((R >> 3) == h) {   // wave-uniform branch
                    float4 c0 = *(const float4*)&C_lds[R][0];
                    float4 c1 = *(const float4*)&C_lds[R][4];
                    float4 c2 = *(const float4*)&C_lds[R][8];
                    float4 c3 = *(const float4*)&C_lds[R][12];
                    float d = c0.x*t0.x + c0.y*t0.y + c0.z*t0.z + c0.w*t0.w
                            + c1.x*t1.x + c1.y*t1.y + c1.z*t1.z + c1.w*t1.w
                            + c2.x*t2.x + c2.y*t2.y + c2.z*t2.z + c2.w*t2.w
                            + c3.x*t3.x + c3.y*t3.y + c3.z*t3.z + c3.w*t3.w;
                    sv[R & 7] += d;
                }
            }
#pragma unroll
            for (int b = 0; b < 8; ++b) {
                tcoT[h * 8 + b][k] = fast_tanh(st[b]);
                pcoT[h * 8 + b][k] = fast_tanh(sv[b]);
            }
        }
        __syncthreads();

        // ---- step 4: scores + shuffle-softmax over b (no barriers) ----
        {
            int a = tid >> 4, b = tid & 15;
            const float* hT = whtT + a * KDIM;
            const float* pT = whpT + a * KDIM;
            float s_t = 0.f, s_v = 0.f;
#pragma unroll 8
            for (int kk = 0; kk < KDIM; kk += 4) {
                float4 ht = *(const float4*)(hT + kk);
                float4 hp = *(const float4*)(pT + kk);
                float4 tc = *(const float4*)&tcoT[b][kk];
                float4 pc = *(const float4*)&pcoT[b][kk];
                s_t += ht.x*tc.x + ht.y*tc.y + ht.z*tc.z + ht.w*tc.w;
                s_v += hp.x*pc.x + hp.y*pc.y + hp.z*pc.z + hp.w*pc.w;
            }
            float mt = s_t, mv = s_v;
#pragma unroll
            for (int o = 8; o; o >>= 1) {
                mt = fmaxf(mt, __shfl_xor(mt, o));
                mv = fmaxf(mv, __shfl_xor(mv, o));
            }
            float et = __expf(s_t - mt), ev = __expf(s_v - mv);
            float dt = et, dv = ev;
#pragma unroll
            for (int o = 8; o; o >>= 1) {
                dt += __shfl_xor(dt, o);
                dv += __shfl_xor(dv, o);
            }
            et = __fdividef(et, dt);
            ev = __fdividef(ev, dv);
            att_acc += et;          // team attention only needs the sum over n
            attp[a][b] = ev;
        }
        __syncthreads();

        // ---- step 5: player_out[a][d] = sum_b attp[a][b] * sp[b][d] ----
        {
            int a = tid >> 4, c = tid & 15;
            float4 o0 = {0.f, 0.f, 0.f, 0.f}, o1 = {0.f, 0.f, 0.f, 0.f};
#pragma unroll
            for (int b = 0; b < ASPECTS; ++b) {
                float w = attp[a][b];
                float4 s0 = *(const float4*)&sp[b][c * 4];
                float4 s1 = *(const float4*)&sp[b][c * 4 + 64];
                o0.x += w * s0.x; o0.y += w * s0.y; o0.z += w * s0.z; o0.w += w * s0.w;
                o1.x += w * s1.x; o1.y += w * s1.y; o1.z += w * s1.z; o1.w += w * s1.w;
            }
            float* orow = pout + (size_t)node * HIDDEN + a * ADIM;
            *(float4*)&orow[c * 4]      = o0;
            *(float4*)&orow[c * 4 + 64] = o1;
        }
    }

    atomicAdd(&attsum[(blockIdx.x & (SLOTS - 1)) * 256 + tid], att_acc);
}

// ---------------------------------------------------------------------------
// epilogue: out0[a][d] = (1/N) * sum_b (sum_n att_t[n][a][b]) * team[b*128+d]
// ---------------------------------------------------------------------------
__global__ void epi_kernel(const float* __restrict__ team,
                           const float* __restrict__ attsum,
                           float* __restrict__ out0, float inv_n) {
    int a = blockIdx.x;
    int tid = threadIdx.x;
    __shared__ float ab[ASPECTS];
    if (tid < ASPECTS) {
        float s = 0.f;
        for (int slot = 0; slot < SLOTS; ++slot)
            s += attsum[slot * 256 + a * ASPECTS + tid];
        ab[tid] = s * inv_n;
    }
    __syncthreads();
    float o = 0.f;
#pragma unroll
    for (int b = 0; b < ASPECTS; ++b)
        o += ab[b] * team[b * ADIM + tid];
    out0[a * ADIM + tid] = o;
}

extern "C" void kernel_launch(void* const* d_in, const int* in_sizes, int n_in,
                              void* d_out, int out_size, void* d_ws, size_t ws_size,
                              hipStream_t stream) {
    const float* team   = (const float*)d_in[0];
    const float* player = (const float*)d_in[1];
    const float* w_b    = (const float*)d_in[2];
    const float* w_t    = (const float*)d_in[3];
    const float* w_p    = (const float*)d_in[4];
    const float* w_ht   = (const float*)d_in[5];
    const float* w_hp   = (const float*)d_in[6];
    float* out = (float*)d_out;

    int n = in_sizes[1] / HIDDEN;   // 32768

    // Workspace layout: 26624 floats total (106 KB).
    float* wbt    = (float*)d_ws;              // 2048
    float* wtt    = wbt + 2048;                // 2048
    float* attsum = wtt + 2048;                // SLOTS*256 = 16384
    float* whtT   = attsum + SLOTS * 256;      // 2048
    float* whpT   = whtT + 2048;               // 2048
    unsigned short* wbtf_hi = (unsigned short*)(whpT + 2048);  // 2048 shorts
    unsigned short* wbtf_lo = wbtf_hi + 2048;                  // 2048 shorts

    hipMemsetAsync(attsum, 0, SLOTS * 256 * sizeof(float), stream);
    prep_kernel<<<ASPECTS, ADIM, 0, stream>>>(team, w_b, w_t, wbt, wtt);
    prep2_kernel<<<1, 256, 0, stream>>>(wbt, w_ht, w_hp, wbtf_hi, wbtf_lo, whtT, whpT);
    coattn_main<<<GRID, 256, 0, stream>>>(player, w_p, wtt, whtT, whpT,
                                          wbtf_hi, wbtf_lo,
                                          out + HIDDEN, attsum, n);
    epi_kernel<<<ASPECTS, ADIM, 0, stream>>>(team, attsum, out, 1.0f / (float)n);
}

// Round 5
// 1084.893 us; speedup vs baseline: 2.2848x; 2.2802x over previous
//
#include <hip/hip_runtime.h>

// Problem constants (fixed by the reference)
#define ASPECTS 16
#define ADIM    128
#define KDIM    128
#define HIDDEN  2048   // ASPECTS*ADIM
#define GRID    4096   // persistent blocks; each handles n/GRID nodes
#define SLOTS   64     // attsum partial-sum slots (1 atomic per thread per block total)

using f32x4  = __attribute__((ext_vector_type(4))) float;
using i32x4  = __attribute__((ext_vector_type(4))) int;
using bf16x8 = __attribute__((ext_vector_type(8))) short;

// Split two fp32 into packed (bf16-hi, bf16-lo-residual) words.
__device__ __forceinline__ void split2(float a, float b, int& hi, int& lo) {
    unsigned ua = __float_as_uint(a);
    unsigned ub = __float_as_uint(b);
    float ra = a - __uint_as_float(ua & 0xffff0000u);   // exact residual
    float rb = b - __uint_as_float(ub & 0xffff0000u);
    hi = (int)((ua >> 16) | (ub & 0xffff0000u));
    lo = (int)((__float_as_uint(ra) >> 16) | (__float_as_uint(rb) & 0xffff0000u));
}

// 8 fp32 -> hi/lo bf16x8 fragments; x = hi + lo + O(2^-16 |x|).
__device__ __forceinline__ void split8(float4 q0, float4 q1, bf16x8& hi, bf16x8& lo) {
    int h0, l0, h1, l1, h2, l2, h3, l3;
    split2(q0.x, q0.y, h0, l0);
    split2(q0.z, q0.w, h1, l1);
    split2(q1.x, q1.y, h2, l2);
    split2(q1.z, q1.w, h3, l3);
    i32x4 H = {h0, h1, h2, h3};
    i32x4 L = {l0, l1, l2, l3};
    hi = __builtin_bit_cast(bf16x8, H);
    lo = __builtin_bit_cast(bf16x8, L);
}

__device__ __forceinline__ float fast_tanh(float x) {
    // tanh(x) = 1 - 2/(e^{2x}+1); exact at +-inf, ~1e-7 error elsewhere
    return 1.0f - __fdividef(2.0f, __expf(2.0f * x) + 1.0f);
}

// ---------------------------------------------------------------------------
// prep: wbt[d][a] = sum_j w_b[d][j] * team[a*128+j]
//       wtt[k][a] = sum_j w_t[k][j] * team[a*128+j]
// grid 16 (a), block 128 (row index)
// ---------------------------------------------------------------------------
__global__ void prep_kernel(const float* __restrict__ team,
                            const float* __restrict__ w_b,
                            const float* __restrict__ w_t,
                            float* __restrict__ wbt,   // [128][16]
                            float* __restrict__ wtt) { // [128][16]
    int a = blockIdx.x;
    int i = threadIdx.x;
    __shared__ float ta[ADIM];
    ta[i] = team[a * ADIM + i];
    __syncthreads();
    const float* wbr = w_b + i * ADIM;
    const float* wtr = w_t + i * ADIM;
    float s1 = 0.f, s2 = 0.f;
#pragma unroll 4
    for (int j = 0; j < ADIM; ++j) {
        s1 += wbr[j] * ta[j];
        s2 += wtr[j] * ta[j];
    }
    wbt[i * ASPECTS + a] = s1;
    wtt[i * ASPECTS + a] = s2;
}

// ---------------------------------------------------------------------------
// prep2: pack wbt into MFMA B-fragments (hi/lo bf16) and transpose w_ht/w_hp.
// B-frag for mfma_f32_16x16x32_bf16: lane l -> col=l&15, k = (l>>4)*8 + j
// grid 1, block 256
// ---------------------------------------------------------------------------
__global__ void prep2_kernel(const float* __restrict__ wbt,   // [128][16]
                             const float* __restrict__ w_ht,  // [128][16]
                             const float* __restrict__ w_hp,  // [128][16]
                             unsigned short* __restrict__ wf_hi,  // [4][64][8]
                             unsigned short* __restrict__ wf_lo,
                             float* __restrict__ whtT,   // [16][128]
                             float* __restrict__ whpT) { // [16][128]
    int t = threadIdx.x;
    int s = t >> 6, l = t & 63;
    int b = l & 15, g = l >> 4;
#pragma unroll
    for (int j = 0; j < 8; ++j) {
        int d = s * 32 + g * 8 + j;
        float x = wbt[d * ASPECTS + b];
        unsigned u = __float_as_uint(x);
        float r = x - __uint_as_float(u & 0xffff0000u);
        wf_hi[(s * 64 + l) * 8 + j] = (unsigned short)(u >> 16);
        wf_lo[(s * 64 + l) * 8 + j] = (unsigned short)(__float_as_uint(r) >> 16);
    }
#pragma unroll
    for (int j = 0; j < 8; ++j) {
        int flat = t * 8 + j;           // 0..2047 = a*128 + kk
        int a = flat >> 7, kk = flat & 127;
        whtT[flat] = w_ht[kk * ASPECTS + a];
        whpT[flat] = w_hp[kk * ASPECTS + a];
    }
}

// ---------------------------------------------------------------------------
// main: persistent blocks, 256 threads (4 waves), grid-stride over nodes.
// Steps 1+2 on MFMA (split-bf16, fp32-accurate); steps 3-5 on VALU.
// launch_bounds (256,2): 256-reg/wave cap so the 16 persistent bf16x8
// w_p fragments stay register-resident (at (256,3) they spilled to scratch:
// 7.4 GB HBM scratch traffic, 2.2 ms).
// ---------------------------------------------------------------------------
__global__ __launch_bounds__(256, 2)
void coattn_main(const float* __restrict__ player,  // [N][2048]
                 const float* __restrict__ w_p,     // [128][128]
                 const float* __restrict__ wtt,     // [128][16]
                 const float* __restrict__ whtT,    // [16][128]
                 const float* __restrict__ whpT,    // [16][128]
                 const unsigned short* __restrict__ wbtf_hi,
                 const unsigned short* __restrict__ wbtf_lo,
                 float* __restrict__ pout,          // [N][2048]
                 float* __restrict__ attsum,        // [SLOTS][256]
                 int total) {
    const int tid = threadIdx.x;
    const int l   = tid & 63;       // lane in wave
    const int wv  = tid >> 6;       // wave 0..3

    __shared__ __align__(16) float sp[ASPECTS][132];     // player aspects (fp32)
    __shared__ __align__(16) float C_lds[ASPECTS][20];   // tanh(p . wbt)
    __shared__ __align__(16) float wpp[KDIM][20];        // wp_p[k][a]
    __shared__ __align__(16) float tcoT[ASPECTS][132];   // team_co transposed [b][k]
    __shared__ __align__(16) float pcoT[ASPECTS][132];   // player_co transposed
    __shared__ float attp[ASPECTS][17];

    // ---- persistent A-fragments of w_p: wave wv owns k-rows [wv*32, wv*32+32) ----
    // A-frag: lane l -> row = tile*16 + (l&15), k = s*32 + (l>>4)*8 + j
    bf16x8 ahi0[4], alo0[4], ahi1[4], alo1[4];
    {
        int ar = l & 15, ag = l >> 4;
        const float* w0 = w_p + ((wv * 2 + 0) * 16 + ar) * ADIM + ag * 8;
        const float* w1 = w_p + ((wv * 2 + 1) * 16 + ar) * ADIM + ag * 8;
#pragma unroll
        for (int s = 0; s < 4; ++s) {
            float4 q0 = *(const float4*)(w0 + s * 32);
            float4 q1 = *(const float4*)(w0 + s * 32 + 4);
            split8(q0, q1, ahi0[s], alo0[s]);
            float4 r0 = *(const float4*)(w1 + s * 32);
            float4 r1 = *(const float4*)(w1 + s * 32 + 4);
            split8(r0, r1, ahi1[s], alo1[s]);
        }
    }

    float att_acc = 0.0f;

    int node = blockIdx.x;
    float4 pf0, pf1;
    if (node < total) {
        const float4* pr = (const float4*)(player + (size_t)node * HIDDEN);
        pf0 = pr[tid];
        pf1 = pr[tid + 256];
    }

    for (; node < total; node += GRID) {
        __syncthreads();   // previous iteration's sp/attp readers done
        {
            int i0 = tid, i1 = tid + 256;
            *(float4*)&sp[i0 >> 5][(i0 & 31) * 4] = pf0;
            *(float4*)&sp[i1 >> 5][(i1 & 31) * 4] = pf1;
        }
        int nxt = node + GRID;
        if (nxt < total) {   // prefetch next node during compute
            const float4* pr = (const float4*)(player + (size_t)nxt * HIDDEN);
            pf0 = pr[tid];
            pf1 = pr[tid + 256];
        }
        __syncthreads();   // sp ready

        // ---- MFMA: wpp = w_p @ P^T (all waves), C = tanh(P @ wbt) (wave 0) ----
        f32x4 accW0 = {0.f, 0.f, 0.f, 0.f};
        f32x4 accW1 = {0.f, 0.f, 0.f, 0.f};
        f32x4 accC  = {0.f, 0.f, 0.f, 0.f};
        {
            int br = l & 15, bg = l >> 4;
#pragma unroll
            for (int s = 0; s < 4; ++s) {
                const float* src = &sp[br][s * 32 + bg * 8];
                float4 q0 = *(const float4*)(src);
                float4 q1 = *(const float4*)(src + 4);
                bf16x8 bhi, blo;
                split8(q0, q1, bhi, blo);
                accW0 = __builtin_amdgcn_mfma_f32_16x16x32_bf16(ahi0[s], bhi, accW0, 0, 0, 0);
                accW1 = __builtin_amdgcn_mfma_f32_16x16x32_bf16(ahi1[s], bhi, accW1, 0, 0, 0);
                if (wv == 0) {
                    bf16x8 wh = *(const bf16x8*)&wbtf_hi[(s * 64 + l) * 8];
                    bf16x8 wl = *(const bf16x8*)&wbtf_lo[(s * 64 + l) * 8];
                    accC = __builtin_amdgcn_mfma_f32_16x16x32_bf16(bhi, wh, accC, 0, 0, 0);
                    accC = __builtin_amdgcn_mfma_f32_16x16x32_bf16(bhi, wl, accC, 0, 0, 0);
                    accC = __builtin_amdgcn_mfma_f32_16x16x32_bf16(blo, wh, accC, 0, 0, 0);
                }
                accW0 = __builtin_amdgcn_mfma_f32_16x16x32_bf16(ahi0[s], blo, accW0, 0, 0, 0);
                accW1 = __builtin_amdgcn_mfma_f32_16x16x32_bf16(ahi1[s], blo, accW1, 0, 0, 0);
                accW0 = __builtin_amdgcn_mfma_f32_16x16x32_bf16(alo0[s], bhi, accW0, 0, 0, 0);
                accW1 = __builtin_amdgcn_mfma_f32_16x16x32_bf16(alo1[s], bhi, accW1, 0, 0, 0);
            }
            // C/D layout (harness-validated): col = lane&15, row = (lane>>4)*4 + reg
            int g = l >> 4, col = l & 15;
            if (wv == 0) {
#pragma unroll
                for (int r = 0; r < 4; ++r)
                    C_lds[g * 4 + r][col] = fast_tanh(accC[r]);
            }
            int row0 = (wv * 2 + 0) * 16 + g * 4;
            int row1 = (wv * 2 + 1) * 16 + g * 4;
#pragma unroll
            for (int r = 0; r < 4; ++r) wpp[row0 + r][col] = accW0[r];
#pragma unroll
            for (int r = 0; r < 4; ++r) wpp[row1 + r][col] = accW1[r];
        }
        __syncthreads();

        // ---- step 3: tco/pco; thread owns (k, half-of-b) ----
        {
            int k = tid & 127, h = tid >> 7;   // h wave-uniform
            float4 w0 = *(const float4*)&wpp[k][0];
            float4 w1 = *(const float4*)&wpp[k][4];
            float4 w2 = *(const float4*)&wpp[k][8];
            float4 w3 = *(const float4*)&wpp[k][12];
            float4 t0 = *(const float4*)&wtt[k * ASPECTS];
            float4 t1 = *(const float4*)&wtt[k * ASPECTS + 4];
            float4 t2 = *(const float4*)&wtt[k * ASPECTS + 8];
            float4 t3 = *(const float4*)&wtt[k * ASPECTS + 12];
            float st[8], sv[8];
            if (h == 0) {
                st[0]=t0.x; st[1]=t0.y; st[2]=t0.z; st[3]=t0.w;
                st[4]=t1.x; st[5]=t1.y; st[6]=t1.z; st[7]=t1.w;
                sv[0]=w0.x; sv[1]=w0.y; sv[2]=w0.z; sv[3]=w0.w;
                sv[4]=w1.x; sv[5]=w1.y; sv[6]=w1.z; sv[7]=w1.w;
            } else {
                st[0]=t2.x; st[1]=t2.y; st[2]=t2.z; st[3]=t2.w;
                st[4]=t3.x; st[5]=t3.y; st[6]=t3.z; st[7]=t3.w;
                sv[0]=w2.x; sv[1]=w2.y; sv[2]=w2.z; sv[3]=w2.w;
                sv[4]=w3.x; sv[5]=w3.y; sv[6]=w3.z; sv[7]=w3.w;
            }
#pragma unroll
            for (int R = 0; R < 16; ++R) {
                float wR = (R < 4)  ? (R == 0 ? w0.x : R == 1 ? w0.y : R == 2 ? w0.z : w0.w)
                         : (R < 8)  ? (R == 4 ? w1.x : R == 5 ? w1.y : R == 6 ? w1.z : w1.w)
                         : (R < 12) ? (R == 8 ? w2.x : R == 9 ? w2.y : R == 10 ? w2.z : w2.w)
                                    : (R == 12 ? w3.x : R == 13 ? w3.y : R == 14 ? w3.z : w3.w);
                float4 cO0 = *(const float4*)&C_lds[R][h * 8];
                float4 cO1 = *(const float4*)&C_lds[R][h * 8 + 4];
                st[0] += wR * cO0.x; st[1] += wR * cO0.y;
                st[2] += wR * cO0.z; st[3] += wR * cO0.w;
                st[4] += wR * cO1.x; st[5] += wR * cO1.y;
                st[6] += wR * cO1.z; st[7] += wR * cO1.w;
                if ((R >> 3) == h) {   // wave-uniform branch
                    float4 c0 = *(const float4*)&C_lds[R][0];
                    float4 c1 = *(const float4*)&C_lds[R][4];
                    float4 c2 = *(const float4*)&C_lds[R][8];
                    float4 c3 = *(const float4*)&C_lds[R][12];
                    float d = c0.x*t0.x + c0.y*t0.y + c0.z*t0.z + c0.w*t0.w
                            + c1.x*t1.x + c1.y*t1.y + c1.z*t1.z + c1.w*t1.w
                            + c2.x*t2.x + c2.y*t2.y + c2.z*t2.z + c2.w*t2.w
                            + c3.x*t3.x + c3.y*t3.y + c3.z*t3.z + c3.w*t3.w;
                    sv[R & 7] += d;
                }
            }
#pragma unroll
            for (int b = 0; b < 8; ++b) {
                tcoT[h * 8 + b][k] = fast_tanh(st[b]);
                pcoT[h * 8 + b][k] = fast_tanh(sv[b]);
            }
        }
        __syncthreads();

        // ---- step 4: scores + shuffle-softmax over b (no barriers) ----
        {
            int a = tid >> 4, b = tid & 15;
            const float* hT = whtT + a * KDIM;
            const float* pT = whpT + a * KDIM;
            float s_t = 0.f, s_v = 0.f;
#pragma unroll 8
            for (int kk = 0; kk < KDIM; kk += 4) {
                float4 ht = *(const float4*)(hT + kk);
                float4 hp = *(const float4*)(pT + kk);
                float4 tc = *(const float4*)&tcoT[b][kk];
                float4 pc = *(const float4*)&pcoT[b][kk];
                s_t += ht.x*tc.x + ht.y*tc.y + ht.z*tc.z + ht.w*tc.w;
                s_v += hp.x*pc.x + hp.y*pc.y + hp.z*pc.z + hp.w*pc.w;
            }
            float mt = s_t, mv = s_v;
#pragma unroll
            for (int o = 8; o; o >>= 1) {
                mt = fmaxf(mt, __shfl_xor(mt, o));
                mv = fmaxf(mv, __shfl_xor(mv, o));
            }
            float et = __expf(s_t - mt), ev = __expf(s_v - mv);
            float dt = et, dv = ev;
#pragma unroll
            for (int o = 8; o; o >>= 1) {
                dt += __shfl_xor(dt, o);
                dv += __shfl_xor(dv, o);
            }
            et = __fdividef(et, dt);
            ev = __fdividef(ev, dv);
            att_acc += et;          // team attention only needs the sum over n
            attp[a][b] = ev;
        }
        __syncthreads();

        // ---- step 5: player_out[a][d] = sum_b attp[a][b] * sp[b][d] ----
        {
            int a = tid >> 4, c = tid & 15;
            float4 o0 = {0.f, 0.f, 0.f, 0.f}, o1 = {0.f, 0.f, 0.f, 0.f};
#pragma unroll
            for (int b = 0; b < ASPECTS; ++b) {
                float w = attp[a][b];
                float4 s0 = *(const float4*)&sp[b][c * 4];
                float4 s1 = *(const float4*)&sp[b][c * 4 + 64];
                o0.x += w * s0.x; o0.y += w * s0.y; o0.z += w * s0.z; o0.w += w * s0.w;
                o1.x += w * s1.x; o1.y += w * s1.y; o1.z += w * s1.z; o1.w += w * s1.w;
            }
            float* orow = pout + (size_t)node * HIDDEN + a * ADIM;
            *(float4*)&orow[c * 4]      = o0;
            *(float4*)&orow[c * 4 + 64] = o1;
        }
    }

    atomicAdd(&attsum[(blockIdx.x & (SLOTS - 1)) * 256 + tid], att_acc);
}

// ---------------------------------------------------------------------------
// epilogue: out0[a][d] = (1/N) * sum_b (sum_n att_t[n][a][b]) * team[b*128+d]
// ---------------------------------------------------------------------------
__global__ void epi_kernel(const float* __restrict__ team,
                           const float* __restrict__ attsum,
                           float* __restrict__ out0, float inv_n) {
    int a = blockIdx.x;
    int tid = threadIdx.x;
    __shared__ float ab[ASPECTS];
    if (tid < ASPECTS) {
        float s = 0.f;
        for (int slot = 0; slot < SLOTS; ++slot)
            s += attsum[slot * 256 + a * ASPECTS + tid];
        ab[tid] = s * inv_n;
    }
    __syncthreads();
    float o = 0.f;
#pragma unroll
    for (int b = 0; b < ASPECTS; ++b)
        o += ab[b] * team[b * ADIM + tid];
    out0[a * ADIM + tid] = o;
}

extern "C" void kernel_launch(void* const* d_in, const int* in_sizes, int n_in,
                              void* d_out, int out_size, void* d_ws, size_t ws_size,
                              hipStream_t stream) {
    const float* team   = (const float*)d_in[0];
    const float* player = (const float*)d_in[1];
    const float* w_b    = (const float*)d_in[2];
    const float* w_t    = (const float*)d_in[3];
    const float* w_p    = (const float*)d_in[4];
    const float* w_ht   = (const float*)d_in[5];
    const float* w_hp   = (const float*)d_in[6];
    float* out = (float*)d_out;

    int n = in_sizes[1] / HIDDEN;   // 32768

    // Workspace layout: 26624 floats total (106 KB).
    float* wbt    = (float*)d_ws;              // 2048
    float* wtt    = wbt + 2048;                // 2048
    float* attsum = wtt + 2048;                // SLOTS*256 = 16384
    float* whtT   = attsum + SLOTS * 256;      // 2048
    float* whpT   = whtT + 2048;               // 2048
    unsigned short* wbtf_hi = (unsigned short*)(whpT + 2048);  // 2048 shorts
    unsigned short* wbtf_lo = wbtf_hi + 2048;                  // 2048 shorts

    hipMemsetAsync(attsum, 0, SLOTS * 256 * sizeof(float), stream);
    prep_kernel<<<ASPECTS, ADIM, 0, stream>>>(team, w_b, w_t, wbt, wtt);
    prep2_kernel<<<1, 256, 0, stream>>>(wbt, w_ht, w_hp, wbtf_hi, wbtf_lo, whtT, whpT);
    coattn_main<<<GRID, 256, 0, stream>>>(player, w_p, wtt, whtT, whpT,
                                          wbtf_hi, wbtf_lo,
                                          out + HIDDEN, attsum, n);
    epi_kernel<<<ASPECTS, ADIM, 0, stream>>>(team, attsum, out, 1.0f / (float)n);
}